// Round 1
// baseline (246.638 us; speedup 1.0000x reference)
//
#include <hip/hip_runtime.h>
#include <math.h>

// Problem constants (match reference)
#define HID   2048   // hidden dim (K)
#define NROW  16384  // B*T rows (M)
#define NCOL  168    // 32 init + 128 op + 8 gate (N, real)
#define NPAD  192    // padded N for 16x12 thread tile
#define NSLOT 16
#define NSTEP 8

// Tiling
#define BM    32     // rows per block
#define BK    32     // K chunk
#define NTH   256    // threads per block
#define BMP   33     // sH row stride (pad: write-conflict-free, odd ok since a-reads are scalar)
#define WPD   196    // sW row stride (mult of 4 -> aligned b128 reads; %8==4 -> 4-way write conflicts max)
#define CPD   172    // sC row stride

__device__ __forceinline__ const float* wrow(int o,
    const float* Wi, const float* Wo, const float* Wg) {
  if (o < 32)  return Wi + (size_t)o * HID;
  if (o < 160) return Wo + (size_t)(o - 32) * HID;
  return Wg + (size_t)(o - 160) * HID;
}

__global__ __launch_bounds__(NTH, 2)
void dag_fused(const float* __restrict__ hidden,
               const float* __restrict__ W_init, const float* __restrict__ b_init,
               const float* __restrict__ W_op,   const float* __restrict__ b_op,
               const float* __restrict__ W_gate, const float* __restrict__ b_gate,
               float* __restrict__ out)
{
  __shared__ float sH[BK][BMP];   //  4224 B : H tile, transposed [k][row]
  __shared__ float sW[BK][WPD];   // 25088 B : W tile, transposed [k][col]
  __shared__ float sC[BM][CPD];   // 22016 B : output tile for the DAG epilogue

  const int tid  = threadIdx.x;
  const int row0 = blockIdx.x * BM;

  // GEMM thread tile: 16 threads along N (TN=12), 16 along M (TM=2)
  const int tn = tid & 15;
  const int tm = tid >> 4;
  const int rm = tm * 2;       // local rows rm, rm+1
  const int cn = tn * 12;      // cols cn..cn+11 (cols >= 168 are pad/garbage, never stored)

  // --- staging geometry ---
  // H: 32 rows x 32 k = 256 float4; 1 per thread. row = tid>>3, k4 = (tid&7)*4
  const int hrow = tid >> 3;
  const int hk   = (tid & 7) * 4;
  const float* hsrc = hidden + (size_t)(row0 + hrow) * HID + hk;

  // W: 168 rows x 32 k = 1344 float4; 5.25 per thread (6th iter only for tid<64)
  const float* wsrc[6];
  int wo[6], wk[6];
  #pragma unroll
  for (int i = 0; i < 6; ++i) {
    int idx = tid + i * NTH;
    if (idx < 1344) {
      wo[i] = idx >> 3;
      wk[i] = (idx & 7) * 4;
      wsrc[i] = wrow(wo[i], W_init, W_op, W_gate) + wk[i];
    } else { wo[i] = 0; wk[i] = 0; wsrc[i] = hidden; }
  }
  const bool w5 = (tid + 5 * NTH) < 1344;

  float acc[2][12];
  #pragma unroll
  for (int i = 0; i < 2; ++i)
    #pragma unroll
    for (int j = 0; j < 12; ++j) acc[i][j] = 0.f;

  // software pipeline: preload chunk 0 into registers
  float4 hp, wp[6];
  hp = *(const float4*)(hsrc);
  #pragma unroll
  for (int i = 0; i < 5; ++i) wp[i] = *(const float4*)(wsrc[i]);
  if (w5) wp[5] = *(const float4*)(wsrc[5]);

  for (int kc = 0; kc < HID; kc += BK) {
    __syncthreads();             // previous compute done reading LDS
    // regs -> LDS (transposed scatter)
    sH[hk+0][hrow] = hp.x; sH[hk+1][hrow] = hp.y;
    sH[hk+2][hrow] = hp.z; sH[hk+3][hrow] = hp.w;
    #pragma unroll
    for (int i = 0; i < 5; ++i) {
      sW[wk[i]+0][wo[i]] = wp[i].x; sW[wk[i]+1][wo[i]] = wp[i].y;
      sW[wk[i]+2][wo[i]] = wp[i].z; sW[wk[i]+3][wo[i]] = wp[i].w;
    }
    if (w5) {
      sW[wk[5]+0][wo[5]] = wp[5].x; sW[wk[5]+1][wo[5]] = wp[5].y;
      sW[wk[5]+2][wo[5]] = wp[5].z; sW[wk[5]+3][wo[5]] = wp[5].w;
    }
    __syncthreads();
    // prefetch next chunk (overlaps with compute below; vmcnt waited at next store)
    if (kc + BK < HID) {
      hp = *(const float4*)(hsrc + kc + BK);
      #pragma unroll
      for (int i = 0; i < 5; ++i) wp[i] = *(const float4*)(wsrc[i] + kc + BK);
      if (w5) wp[5] = *(const float4*)(wsrc[5] + kc + BK);
    }
    // inner product on current LDS tile
    #pragma unroll
    for (int k = 0; k < BK; ++k) {
      const float a0 = sH[k][rm];
      const float a1 = sH[k][rm + 1];
      float bb[12];
      *(float4*)&bb[0] = *(const float4*)&sW[k][cn];
      *(float4*)&bb[4] = *(const float4*)&sW[k][cn + 4];
      *(float4*)&bb[8] = *(const float4*)&sW[k][cn + 8];
      #pragma unroll
      for (int j = 0; j < 12; ++j) {
        acc[0][j] = fmaf(a0, bb[j], acc[0][j]);
        acc[1][j] = fmaf(a1, bb[j], acc[1][j]);
      }
    }
  }

  // C tile -> LDS for the epilogue (only real cols)
  #pragma unroll
  for (int i = 0; i < 2; ++i) {
    #pragma unroll
    for (int j = 0; j < 12; ++j) {
      int c = cn + j;
      if (c < NCOL) sC[rm + i][c] = acc[i][j];
    }
  }
  __syncthreads();

  // --- per-row sequential DAG: one thread per row ---
  if (tid < BM) {
    const int r = tid;
    float Vm[NSLOT], Vs[NSLOT];
    #pragma unroll
    for (int i = 0; i < NSLOT; ++i) {
      float mv = sC[r][i]        + b_init[i];
      float sv = sC[r][16 + i]   + b_init[16 + i];
      Vm[i] = fabsf(mv);
      Vs[i] = tanhf(sv);
    }
    float G[NSTEP];
    #pragma unroll
    for (int s = 0; s < NSTEP; ++s) {
      float gr = sC[r][160 + s] + b_gate[s];
      G[s] = 1.0f / (1.0f + expf(-gr));
    }
    #pragma unroll
    for (int s = 0; s < NSTEP; ++s) {
      const float g = G[s];
      float R = 0.f, sp = 1.f;
      #pragma unroll
      for (int i = 0; i < NSLOT; ++i) {
        // mask: pos < 8+s  (compile-time per (s,i))
        float Osi = (i < 8 + s) ? (sC[r][32 + s * 16 + i] + b_op[s * 16 + i]) : 0.f;
        float sgn   = Vs[i] * Vm[i];
        float logm  = logf(fmaxf(Vm[i], 1e-12f));
        float mixed = logm * (1.f - g) + sgn * g;
        R  += Osi * mixed;                 // masked slots contribute exactly 0
        sp *= Vs[i] * (fabsf(Osi) + 1.f);  // V_sign of ALL 16 slots participates
      }
      float lin_sign = tanhf(R  / 1e-4f);
      float log_sign = tanhf(sp / 1e-4f);
      float vs_new = g * lin_sign + (1.f - g) * log_sign;
      float vm_new = g * fabsf(R) + (1.f - g) * expf(fminf(R, 23.026f));
      Vm[8 + s] = vm_new;
      Vs[8 + s] = vs_new;
    }
    out[row0 + r] = Vs[NSLOT - 1] * Vm[NSLOT - 1];
  }
}

extern "C" void kernel_launch(void* const* d_in, const int* in_sizes, int n_in,
                              void* d_out, int out_size, void* d_ws, size_t ws_size,
                              hipStream_t stream) {
  const float* hidden = (const float*)d_in[0];
  const float* W_init = (const float*)d_in[1];
  const float* b_init = (const float*)d_in[2];
  const float* W_op   = (const float*)d_in[3];
  const float* b_op   = (const float*)d_in[4];
  const float* W_gate = (const float*)d_in[5];
  const float* b_gate = (const float*)d_in[6];
  float* out = (float*)d_out;

  dim3 grid(NROW / BM);   // 512 blocks -> 2 blocks/CU
  dim3 block(NTH);
  dag_fused<<<grid, block, 0, stream>>>(hidden, W_init, b_init, W_op, b_op,
                                        W_gate, b_gate, out);
}

// Round 2
// 133.789 us; speedup vs baseline: 1.8435x; 1.8435x over previous
//
#include <hip/hip_runtime.h>
#include <math.h>

#define HID   2048
#define NROW  16384
#define NCOL  168
#define BM    64
#define KSTEPS 64     // 2048 / 32
#define CPD   172     // sC row stride (f32)
#define NSLOT 16
#define NSTEP 8

typedef short short8 __attribute__((ext_vector_type(8)));
typedef float f32x4  __attribute__((ext_vector_type(4)));
typedef unsigned int u32x4 __attribute__((ext_vector_type(4)));

static __device__ __forceinline__ unsigned pack_hi(unsigned u0, unsigned u1) {
  return (u0 >> 16) | (u1 & 0xFFFF0000u);   // [bf16(x1) : bf16(x0)] truncated
}

// 3-way bf16 split (truncation at each level; residual <= 2^-24 |x|)
struct Planes { u32x4 p1, p2, p3; };
static __device__ __forceinline__ Planes split8(const float* x) {
  Planes P;
  #pragma unroll
  for (int q = 0; q < 4; ++q) {
    float x0 = x[2*q], x1 = x[2*q+1];
    unsigned u0 = __float_as_uint(x0), u1 = __float_as_uint(x1);
    P.p1[q] = pack_hi(u0, u1);
    float r0 = x0 - __uint_as_float(u0 & 0xFFFF0000u);
    float r1 = x1 - __uint_as_float(u1 & 0xFFFF0000u);
    unsigned v0 = __float_as_uint(r0), v1 = __float_as_uint(r1);
    P.p2[q] = pack_hi(v0, v1);
    float s0 = r0 - __uint_as_float(v0 & 0xFFFF0000u);
    float s1 = r1 - __uint_as_float(v1 & 0xFFFF0000u);
    P.p3[q] = pack_hi(__float_as_uint(s0), __float_as_uint(s1));
  }
  return P;
}

static __device__ __forceinline__ void loadA8(const float* p, float* x) {
  float4 a = *(const float4*)p;
  float4 b = *(const float4*)(p + 4);
  x[0]=a.x; x[1]=a.y; x[2]=a.z; x[3]=a.w;
  x[4]=b.x; x[5]=b.y; x[6]=b.z; x[7]=b.w;
}

static __device__ __forceinline__ f32x4 mf(short8 a, short8 b, f32x4 c) {
  return __builtin_amdgcn_mfma_f32_16x16x32_bf16(a, b, c, 0, 0, 0);
}

// ---------------------------------------------------------------------------
// Prep: split W (concat 168x2048, zero-pad to 192) into 3 bf16 planes, laid
// out in ws in MFMA-B fragment-lane order:
//   ws chunk (kidx, nt, pl) = 64 lanes x 16B; lane l holds
//   B[k = kidx*32 + (l>>4)*8 + j][col = nt*16 + (l&15)], j=0..7
// ---------------------------------------------------------------------------
__global__ void prep_b(const float* __restrict__ Wi, const float* __restrict__ Wo,
                       const float* __restrict__ Wg, u32x4* __restrict__ wsB) {
  int bid  = blockIdx.x;          // 64 * 12 = 768
  int kidx = bid / 12;
  int nt   = bid - kidx * 12;
  int l    = threadIdx.x;         // 64
  int col  = nt * 16 + (l & 15);
  int k0   = kidx * 32 + (l >> 4) * 8;

  float x[8];
  if (col < NCOL) {
    const float* wr = (col < 32)  ? (Wi + (size_t)col * HID)
                    : (col < 160) ? (Wo + (size_t)(col - 32) * HID)
                                  : (Wg + (size_t)(col - 160) * HID);
    loadA8(wr + k0, x);
  } else {
    #pragma unroll
    for (int i = 0; i < 8; ++i) x[i] = 0.f;
  }
  Planes P = split8(x);
  size_t base = (size_t)((kidx * 12 + nt) * 3) * 64 + l;
  wsB[base]       = P.p1;
  wsB[base + 64]  = P.p2;
  wsB[base + 128] = P.p3;
}

// ---------------------------------------------------------------------------
// Main fused kernel: 256 blocks x 256 thr (4 waves, 2x2), BM=64, NPAD=192.
// A: global->reg->split (no LDS). B: ws->reg->LDS single buffer (36 KB).
// 6-product split GEMM -> sC (LDS overlay) -> per-row DAG epilogue.
// ---------------------------------------------------------------------------
__global__ __launch_bounds__(256, 1)
void dag_main(const float* __restrict__ hidden, const u32x4* __restrict__ wsB,
              const float* __restrict__ b_init, const float* __restrict__ b_op,
              const float* __restrict__ b_gate, float* __restrict__ out)
{
  __shared__ __align__(16) char smem[44032];   // max(36*1024, 64*172*4)

  const int tid = threadIdx.x;
  const int l   = tid & 63;
  const int w   = tid >> 6;       // wave 0..3
  const int wm  = w >> 1;         // wave row  (0..1): rows wm*32 + mt*16
  const int wn  = w & 1;          // wave col  (0..1): cols wn*96 + j*16
  const int row0 = blockIdx.x * BM;
  const int r   = l & 15;
  const int kg  = l >> 4;

  // A source pointers: lane l covers rows (wm*32 + mt*16 + r), k = t*32 + kg*8
  const float* ap0 = hidden + (size_t)(row0 + wm * 32 + r) * HID + kg * 8;
  const float* ap1 = ap0 + (size_t)16 * HID;

  // B staging: wave w owns chunks [9w, 9w+9)
  const u32x4* bsrc = wsB + (size_t)(9 * w) * 64 + l;       // + t*36*64 + i*64
  u32x4* bdst = (u32x4*)smem + (9 * w) * 64 + l;            // + i*64
  const short8* brd = (const short8*)smem + (wn * 18) * 64 + l;  // + (j*3+pl)*64

  f32x4 acc[2][6];
  const f32x4 zf = {0.f, 0.f, 0.f, 0.f};
  #pragma unroll
  for (int mt = 0; mt < 2; ++mt)
    #pragma unroll
    for (int j = 0; j < 6; ++j) acc[mt][j] = zf;

  float xs0[8], xs1[8];
  u32x4 bst[9];

  // prologue: load A(0), B(0); write B(0) to LDS
  loadA8(ap0, xs0);
  loadA8(ap1, xs1);
  #pragma unroll
  for (int i = 0; i < 9; ++i) bst[i] = bsrc[i * 64];
  #pragma unroll
  for (int i = 0; i < 9; ++i) bdst[i * 64] = bst[i];
  __syncthreads();

  for (int t = 0; t < KSTEPS; ++t) {
    // split current A into fragments (registers only)
    Planes PA0 = split8(xs0);
    Planes PA1 = split8(xs1);
    short8 a0p1 = __builtin_bit_cast(short8, PA0.p1);
    short8 a0p2 = __builtin_bit_cast(short8, PA0.p2);
    short8 a0p3 = __builtin_bit_cast(short8, PA0.p3);
    short8 a1p1 = __builtin_bit_cast(short8, PA1.p1);
    short8 a1p2 = __builtin_bit_cast(short8, PA1.p2);
    short8 a1p3 = __builtin_bit_cast(short8, PA1.p3);

    // issue next-tile global loads (hidden + ws) to hide latency under MFMA
    if (t < KSTEPS - 1) {
      loadA8(ap0 + (t + 1) * 32, xs0);
      loadA8(ap1 + (t + 1) * 32, xs1);
      const u32x4* bs = bsrc + (size_t)(t + 1) * 36 * 64;
      #pragma unroll
      for (int i = 0; i < 9; ++i) bst[i] = bs[i * 64];
    }

    // compute on current B buffer
    #pragma unroll
    for (int j = 0; j < 6; ++j) {
      short8 b1 = brd[(j * 3 + 0) * 64];
      short8 b2 = brd[(j * 3 + 1) * 64];
      short8 b3 = brd[(j * 3 + 2) * 64];
      {
        f32x4 c = acc[0][j];
        c = mf(a0p1, b1, c); c = mf(a0p1, b2, c); c = mf(a0p2, b1, c);
        c = mf(a0p1, b3, c); c = mf(a0p2, b2, c); c = mf(a0p3, b1, c);
        acc[0][j] = c;
      }
      {
        f32x4 c = acc[1][j];
        c = mf(a1p1, b1, c); c = mf(a1p1, b2, c); c = mf(a1p2, b1, c);
        c = mf(a1p1, b3, c); c = mf(a1p2, b2, c); c = mf(a1p3, b1, c);
        acc[1][j] = c;
      }
    }
    __syncthreads();                 // all reads of B buffer done
    if (t < KSTEPS - 1) {
      #pragma unroll
      for (int i = 0; i < 9; ++i) bdst[i * 64] = bst[i];
    }
    __syncthreads();                 // B(t+1) visible
  }

  // epilogue: acc -> sC (overlays the B buffer; safe after final barrier)
  float (*sC)[CPD] = (float(*)[CPD])smem;
  #pragma unroll
  for (int mt = 0; mt < 2; ++mt) {
    #pragma unroll
    for (int j = 0; j < 6; ++j) {
      int col = wn * 96 + j * 16 + r;
      if (col < NCOL) {
        int row = wm * 32 + mt * 16 + kg * 4;
        sC[row + 0][col] = acc[mt][j][0];
        sC[row + 1][col] = acc[mt][j][1];
        sC[row + 2][col] = acc[mt][j][2];
        sC[row + 3][col] = acc[mt][j][3];
      }
    }
  }
  __syncthreads();

  // per-row sequential DAG: one lane per row (wave 0)
  if (tid < BM) {
    const int rr = tid;
    float Vm[NSLOT], Vs[NSLOT];
    #pragma unroll
    for (int i = 0; i < NSLOT; ++i) {
      float mv = sC[rr][i]      + b_init[i];
      float sv = sC[rr][16 + i] + b_init[16 + i];
      Vm[i] = fabsf(mv);
      Vs[i] = tanhf(sv);
    }
    float G[NSTEP];
    #pragma unroll
    for (int s = 0; s < NSTEP; ++s) {
      float gr = sC[rr][160 + s] + b_gate[s];
      G[s] = 1.0f / (1.0f + expf(-gr));
    }
    #pragma unroll
    for (int s = 0; s < NSTEP; ++s) {
      const float g = G[s];
      float R = 0.f, sp = 1.f;
      #pragma unroll
      for (int i = 0; i < NSLOT; ++i) {
        float Osi = (i < 8 + s) ? (sC[rr][32 + s * 16 + i] + b_op[s * 16 + i]) : 0.f;
        float sgn   = Vs[i] * Vm[i];
        float logm  = logf(fmaxf(Vm[i], 1e-12f));
        float mixed = logm * (1.f - g) + sgn * g;
        R  += Osi * mixed;
        sp *= Vs[i] * (fabsf(Osi) + 1.f);
      }
      float lin_sign = tanhf(R  / 1e-4f);
      float log_sign = tanhf(sp / 1e-4f);
      float vs_new = g * lin_sign + (1.f - g) * log_sign;
      float vm_new = g * fabsf(R) + (1.f - g) * expf(fminf(R, 23.026f));
      Vm[8 + s] = vm_new;
      Vs[8 + s] = vs_new;
    }
    out[row0 + rr] = Vs[NSLOT - 1] * Vm[NSLOT - 1];
  }
}

extern "C" void kernel_launch(void* const* d_in, const int* in_sizes, int n_in,
                              void* d_out, int out_size, void* d_ws, size_t ws_size,
                              hipStream_t stream) {
  (void)in_sizes; (void)n_in; (void)out_size; (void)ws_size;
  const float* hidden = (const float*)d_in[0];
  const float* W_init = (const float*)d_in[1];
  const float* b_init = (const float*)d_in[2];
  const float* W_op   = (const float*)d_in[3];
  const float* b_op   = (const float*)d_in[4];
  const float* W_gate = (const float*)d_in[5];
  const float* b_gate = (const float*)d_in[6];
  float* out = (float*)d_out;
  u32x4* wsB = (u32x4*)d_ws;      // needs 64*36*1024 B = 2.25 MiB

  prep_b<<<dim3(768), dim3(64), 0, stream>>>(W_init, W_op, W_gate, wsB);
  dag_main<<<dim3(NROW / BM), dim3(256), 0, stream>>>(hidden, wsB, b_init, b_op,
                                                      b_gate, out);
}

// Round 3
// 118.674 us; speedup vs baseline: 2.0783x; 1.1274x over previous
//
#include <hip/hip_runtime.h>
#include <math.h>

#define HID    2048
#define NROW   16384
#define NCOL   168
#define BM     64
#define KSTEPS 64      // 2048 / 32
#define NCHUNK 33      // 11 col-chunks (176 cols) x 3 planes
#define NELEM  2112    // NCHUNK*64 16B-elements per K-step
#define BUFB   33792   // NELEM*16 bytes per LDS buffer
#define CPD    172     // sC row stride (f32)
#define NSLOT  16
#define NSTEP  8

typedef short short8 __attribute__((ext_vector_type(8)));
typedef float f32x4  __attribute__((ext_vector_type(4)));
typedef unsigned int u32x4 __attribute__((ext_vector_type(4)));

// [bf16(x1) : bf16(x0)] via v_perm_b32 (1 VALU op)
static __device__ __forceinline__ unsigned pack_hi(unsigned u0, unsigned u1) {
  return __builtin_amdgcn_perm(u1, u0, 0x07060302u);
}

// 3-way bf16 split (truncating; combined capture ~24 mantissa bits)
struct Planes { u32x4 p1, p2, p3; };
static __device__ __forceinline__ Planes split8(const float* x) {
  Planes P;
  #pragma unroll
  for (int q = 0; q < 4; ++q) {
    float x0 = x[2*q], x1 = x[2*q+1];
    unsigned u0 = __float_as_uint(x0), u1 = __float_as_uint(x1);
    P.p1[q] = pack_hi(u0, u1);
    float r0 = x0 - __uint_as_float(u0 & 0xFFFF0000u);
    float r1 = x1 - __uint_as_float(u1 & 0xFFFF0000u);
    unsigned v0 = __float_as_uint(r0), v1 = __float_as_uint(r1);
    P.p2[q] = pack_hi(v0, v1);
    float s0 = r0 - __uint_as_float(v0 & 0xFFFF0000u);
    float s1 = r1 - __uint_as_float(v1 & 0xFFFF0000u);
    P.p3[q] = pack_hi(__float_as_uint(s0), __float_as_uint(s1));
  }
  return P;
}

static __device__ __forceinline__ void loadA8(const float* p, float* x) {
  float4 a = *(const float4*)p;
  float4 b = *(const float4*)(p + 4);
  x[0]=a.x; x[1]=a.y; x[2]=a.z; x[3]=a.w;
  x[4]=b.x; x[5]=b.y; x[6]=b.z; x[7]=b.w;
}

static __device__ __forceinline__ f32x4 mf(short8 a, short8 b, f32x4 c) {
  return __builtin_amdgcn_mfma_f32_16x16x32_bf16(a, b, c, 0, 0, 0);
}

// async global->LDS, 16B per lane; LDS dest = wave-uniform base + lane*16
static __device__ __forceinline__ void gld_lds16(const void* g, void* l) {
  __builtin_amdgcn_global_load_lds(
      (const __attribute__((address_space(1))) unsigned int*)g,
      (__attribute__((address_space(3))) unsigned int*)l, 16, 0, 0);
}

// ---------------------------------------------------------------------------
// Prep: split W (concat 168 rows, 11 col-chunks of 16, zero-pad 168..175)
// into 3 bf16 planes in MFMA-B fragment-lane order.
// chunk(kidx, nt, pl): lane l holds B[k=kidx*32+(l>>4)*8+j][col=nt*16+(l&15)]
// ws element index = kidx*2112 + (nt*3+pl)*64 + l   (16B each)
// ---------------------------------------------------------------------------
__global__ void prep_b(const float* __restrict__ Wi, const float* __restrict__ Wo,
                       const float* __restrict__ Wg, u32x4* __restrict__ wsB) {
  int bid  = blockIdx.x;          // 64 * 11 = 704
  int kidx = bid / 11;
  int nt   = bid - kidx * 11;
  int l    = threadIdx.x;         // 64
  int col  = nt * 16 + (l & 15);
  int k0   = kidx * 32 + (l >> 4) * 8;

  float x[8];
  if (col < NCOL) {
    const float* wr = (col < 32)  ? (Wi + (size_t)col * HID)
                    : (col < 160) ? (Wo + (size_t)(col - 32) * HID)
                                  : (Wg + (size_t)(col - 160) * HID);
    loadA8(wr + k0, x);
  } else {
    #pragma unroll
    for (int i = 0; i < 8; ++i) x[i] = 0.f;
  }
  Planes P = split8(x);
  size_t base = (size_t)kidx * NELEM + (nt * 3) * 64 + l;
  wsB[base]       = P.p1;
  wsB[base + 64]  = P.p2;
  wsB[base + 128] = P.p3;
}

// ---------------------------------------------------------------------------
// Main: 256 blocks x 512 thr (8 waves, 2 wm x 4 wn), BM=64.
// Wave tile: 32 rows x 48 cols. A: global->reg->split (no LDS).
// B: ws -> LDS via global_load_lds (double buffer, 1 barrier/K-step).
// ---------------------------------------------------------------------------
__global__ __launch_bounds__(512, 2)
void dag_main(const float* __restrict__ hidden, const u32x4* __restrict__ wsB,
              const float* __restrict__ b_init, const float* __restrict__ b_op,
              const float* __restrict__ b_gate, float* __restrict__ out)
{
  __shared__ __align__(16) char smem[2 * BUFB];   // 67584 B (sC overlays)

  const int tid = threadIdx.x;
  const int l   = tid & 63;
  const int w   = tid >> 6;       // wave 0..7
  const int wm  = w >> 2;         // 0..1 : rows wm*32 + mt*16
  const int wn  = w & 3;          // 0..3 : cols wn*48 + j*16
  const int row0 = blockIdx.x * BM;
  const int r   = l & 15;
  const int kg  = l >> 4;

  // A: lane l covers rows row0 + wm*32 + mt*16 + r, k = t*32 + kg*8
  const float* ap0 = hidden + (size_t)(row0 + wm * 32 + r) * HID + kg * 8;
  const float* ap1 = ap0 + (size_t)16 * HID;

  // B staging pointers
  const u32x4* bsrc = wsB + tid;                  // + t*NELEM + i*512 (per-lane)
  char* wbase = smem + w * 1024;                  // + sel*BUFB + i*8192 (wave-uniform)
  // B fragment read base: chunk (wn*9 + j*3 + pl), byte = chunk*1024 + l*16
  const char* brd0 = smem + (wn * 9 * 64 + l) * 16;

  f32x4 acc[2][3];
  const f32x4 zf = {0.f, 0.f, 0.f, 0.f};
  #pragma unroll
  for (int mt = 0; mt < 2; ++mt)
    #pragma unroll
    for (int j = 0; j < 3; ++j) acc[mt][j] = zf;

  float xs0[8], xs1[8];

#define STAGE(t_, sel_) do {                                   \
    const u32x4* s_ = bsrc + (size_t)NELEM * (t_);             \
    char* d_ = wbase + (sel_) * BUFB;                          \
    gld_lds16(s_,        d_);                                  \
    gld_lds16(s_ + 512,  d_ + 8192);                           \
    gld_lds16(s_ + 1024, d_ + 16384);                          \
    gld_lds16(s_ + 1536, d_ + 24576);                          \
    if (w == 0) gld_lds16(s_ + 2048, d_ + 32768 - w * 1024);   \
  } while (0)

  // prologue: B(0) DMA + A(0) loads; barrier drains vmcnt
  STAGE(0, 0);
  loadA8(ap0, xs0);
  loadA8(ap1, xs1);
  __syncthreads();

  for (int t = 0; t < KSTEPS; ++t) {
    // split current A (registers only)
    Planes PA0 = split8(xs0);
    Planes PA1 = split8(xs1);
    short8 a0p1 = __builtin_bit_cast(short8, PA0.p1);
    short8 a0p2 = __builtin_bit_cast(short8, PA0.p2);
    short8 a0p3 = __builtin_bit_cast(short8, PA0.p3);
    short8 a1p1 = __builtin_bit_cast(short8, PA1.p1);
    short8 a1p2 = __builtin_bit_cast(short8, PA1.p2);
    short8 a1p3 = __builtin_bit_cast(short8, PA1.p3);

    // issue next-tile DMA + A loads (hidden under MFMA; drained at barrier)
    if (t + 1 < KSTEPS) {
      STAGE(t + 1, (t + 1) & 1);
      loadA8(ap0 + (t + 1) * 32, xs0);
      loadA8(ap1 + (t + 1) * 32, xs1);
    }

    // MFMA on current buffer
    const char* bb = brd0 + (t & 1) * BUFB;
    #pragma unroll
    for (int j = 0; j < 3; ++j) {
      if (wn == 3 && j == 2) continue;       // cols 176..191 don't exist
      short8 b1 = *(const short8*)(bb + (j * 3 + 0) * 1024);
      short8 b2 = *(const short8*)(bb + (j * 3 + 1) * 1024);
      short8 b3 = *(const short8*)(bb + (j * 3 + 2) * 1024);
      {
        f32x4 c = acc[0][j];
        c = mf(a0p1, b1, c); c = mf(a0p1, b2, c); c = mf(a0p2, b1, c);
        c = mf(a0p1, b3, c); c = mf(a0p2, b2, c); c = mf(a0p3, b1, c);
        acc[0][j] = c;
      }
      {
        f32x4 c = acc[1][j];
        c = mf(a1p1, b1, c); c = mf(a1p1, b2, c); c = mf(a1p2, b1, c);
        c = mf(a1p1, b3, c); c = mf(a1p2, b2, c); c = mf(a1p3, b1, c);
        acc[1][j] = c;
      }
    }
    __syncthreads();   // drains DMA (vmcnt) + all reads; flip buffers
  }
#undef STAGE

  // epilogue: acc -> sC (overlays LDS; safe after final barrier)
  float (*sC)[CPD] = (float(*)[CPD])smem;
  #pragma unroll
  for (int mt = 0; mt < 2; ++mt) {
    #pragma unroll
    for (int j = 0; j < 3; ++j) {
      int col = wn * 48 + j * 16 + r;
      if (col < NCOL) {
        int row = wm * 32 + mt * 16 + kg * 4;
        sC[row + 0][col] = acc[mt][j][0];
        sC[row + 1][col] = acc[mt][j][1];
        sC[row + 2][col] = acc[mt][j][2];
        sC[row + 3][col] = acc[mt][j][3];
      }
    }
  }
  __syncthreads();

  // per-row sequential DAG: one lane per row
  if (tid < BM) {
    const int rr = tid;
    float Vm[NSLOT], Vs[NSLOT];
    #pragma unroll
    for (int i = 0; i < NSLOT; ++i) {
      float mv = sC[rr][i]      + b_init[i];
      float sv = sC[rr][16 + i] + b_init[16 + i];
      Vm[i] = fabsf(mv);
      Vs[i] = tanhf(sv);
    }
    float G[NSTEP];
    #pragma unroll
    for (int s = 0; s < NSTEP; ++s) {
      float gr = sC[rr][160 + s] + b_gate[s];
      G[s] = 1.0f / (1.0f + expf(-gr));
    }
    #pragma unroll
    for (int s = 0; s < NSTEP; ++s) {
      const float g = G[s];
      float R = 0.f, sp = 1.f;
      #pragma unroll
      for (int i = 0; i < NSLOT; ++i) {
        float Osi = (i < 8 + s) ? (sC[rr][32 + s * 16 + i] + b_op[s * 16 + i]) : 0.f;
        float sgn   = Vs[i] * Vm[i];
        float logm  = logf(fmaxf(Vm[i], 1e-12f));
        float mixed = logm * (1.f - g) + sgn * g;
        R  += Osi * mixed;
        sp *= Vs[i] * (fabsf(Osi) + 1.f);
      }
      float lin_sign = tanhf(R  / 1e-4f);
      float log_sign = tanhf(sp / 1e-4f);
      float vs_new = g * lin_sign + (1.f - g) * log_sign;
      float vm_new = g * fabsf(R) + (1.f - g) * expf(fminf(R, 23.026f));
      Vm[8 + s] = vm_new;
      Vs[8 + s] = vs_new;
    }
    out[row0 + rr] = Vs[NSLOT - 1] * Vm[NSLOT - 1];
  }
}

extern "C" void kernel_launch(void* const* d_in, const int* in_sizes, int n_in,
                              void* d_out, int out_size, void* d_ws, size_t ws_size,
                              hipStream_t stream) {
  (void)in_sizes; (void)n_in; (void)out_size; (void)ws_size;
  const float* hidden = (const float*)d_in[0];
  const float* W_init = (const float*)d_in[1];
  const float* b_init = (const float*)d_in[2];
  const float* W_op   = (const float*)d_in[3];
  const float* b_op   = (const float*)d_in[4];
  const float* W_gate = (const float*)d_in[5];
  const float* b_gate = (const float*)d_in[6];
  float* out = (float*)d_out;
  u32x4* wsB = (u32x4*)d_ws;      // 64 * 2112 * 16 B = 2.06 MiB

  prep_b<<<dim3(704), dim3(64), 0, stream>>>(W_init, W_op, W_gate, wsB);
  dag_main<<<dim3(NROW / BM), dim3(512), 0, stream>>>(hidden, wsB, b_init, b_op,
                                                      b_gate, out);
}

// Round 4
// 114.870 us; speedup vs baseline: 2.1471x; 1.0331x over previous
//
#include <hip/hip_runtime.h>
#include <math.h>

#define HID    2048
#define NROW   16384
#define NCOL   168
#define BM     32      // rows per block
#define KSTEPS 64      // 2048 / 32
#define NCHUNK 33      // 11 col-chunks (176 cols) x 3 planes
#define NELEM  2112    // NCHUNK*64 16B-elements per K-step
#define BUFB   33792   // NELEM*16 bytes per LDS buffer
#define CPD    172     // sC row stride (f32)
#define NSLOT  16
#define NSTEP  8

typedef short short8 __attribute__((ext_vector_type(8)));
typedef float f32x4  __attribute__((ext_vector_type(4)));
typedef unsigned int u32x4 __attribute__((ext_vector_type(4)));

// [bf16(x1) : bf16(x0)] via v_perm_b32 (1 VALU op)
static __device__ __forceinline__ unsigned pack_hi(unsigned u0, unsigned u1) {
  return __builtin_amdgcn_perm(u1, u0, 0x07060302u);
}

// 3-way bf16 split (truncating; combined capture ~24 mantissa bits)
struct Planes { u32x4 p1, p2, p3; };
static __device__ __forceinline__ Planes split8(const float* x) {
  Planes P;
  #pragma unroll
  for (int q = 0; q < 4; ++q) {
    float x0 = x[2*q], x1 = x[2*q+1];
    unsigned u0 = __float_as_uint(x0), u1 = __float_as_uint(x1);
    P.p1[q] = pack_hi(u0, u1);
    float r0 = x0 - __uint_as_float(u0 & 0xFFFF0000u);
    float r1 = x1 - __uint_as_float(u1 & 0xFFFF0000u);
    unsigned v0 = __float_as_uint(r0), v1 = __float_as_uint(r1);
    P.p2[q] = pack_hi(v0, v1);
    float s0 = r0 - __uint_as_float(v0 & 0xFFFF0000u);
    float s1 = r1 - __uint_as_float(v1 & 0xFFFF0000u);
    P.p3[q] = pack_hi(__float_as_uint(s0), __float_as_uint(s1));
  }
  return P;
}

static __device__ __forceinline__ void loadA8(const float* p, float* x) {
  float4 a = *(const float4*)p;
  float4 b = *(const float4*)(p + 4);
  x[0]=a.x; x[1]=a.y; x[2]=a.z; x[3]=a.w;
  x[4]=b.x; x[5]=b.y; x[6]=b.z; x[7]=b.w;
}

static __device__ __forceinline__ f32x4 mf(short8 a, short8 b, f32x4 c) {
  return __builtin_amdgcn_mfma_f32_16x16x32_bf16(a, b, c, 0, 0, 0);
}

// async global->LDS, 16B per lane; LDS dest = wave-uniform base + lane*16
static __device__ __forceinline__ void gld_lds16(const void* g, void* l) {
  __builtin_amdgcn_global_load_lds(
      (const __attribute__((address_space(1))) unsigned int*)g,
      (__attribute__((address_space(3))) unsigned int*)l, 16, 0, 0);
}

// ---------------------------------------------------------------------------
// Prep: split W (concat 168 rows, 11 col-chunks of 16, zero-pad 168..175)
// into 3 bf16 planes in MFMA-B fragment-lane order.
// chunk(kidx, nt, pl): lane l holds B[k=kidx*32+(l>>4)*8+j][col=nt*16+(l&15)]
// ws element index = kidx*2112 + (nt*3+pl)*64 + l   (16B each)
// ---------------------------------------------------------------------------
__global__ void prep_b(const float* __restrict__ Wi, const float* __restrict__ Wo,
                       const float* __restrict__ Wg, u32x4* __restrict__ wsB) {
  int bid  = blockIdx.x;          // 64 * 11 = 704
  int kidx = bid / 11;
  int nt   = bid - kidx * 11;
  int l    = threadIdx.x;         // 64
  int col  = nt * 16 + (l & 15);
  int k0   = kidx * 32 + (l >> 4) * 8;

  float x[8];
  if (col < NCOL) {
    const float* wr = (col < 32)  ? (Wi + (size_t)col * HID)
                    : (col < 160) ? (Wo + (size_t)(col - 32) * HID)
                                  : (Wg + (size_t)(col - 160) * HID);
    loadA8(wr + k0, x);
  } else {
    #pragma unroll
    for (int i = 0; i < 8; ++i) x[i] = 0.f;
  }
  Planes P = split8(x);
  size_t base = (size_t)kidx * NELEM + (nt * 3) * 64 + l;
  wsB[base]       = P.p1;
  wsB[base + 64]  = P.p2;
  wsB[base + 128] = P.p3;
}

// ---------------------------------------------------------------------------
// Main: 512 blocks x 256 thr (4 waves), BM=32 -> 2 independent blocks/CU.
// Wave w covers cols [w*48, w*48+48) x all 32 rows (2 m-subtiles of 16).
// A: global->reg->split (no LDS). B: ws->LDS via global_load_lds, dbuf,
// 1 barrier/K-step. Barrier-drain stalls hidden by the sibling block.
// ---------------------------------------------------------------------------
__global__ __launch_bounds__(256, 2)
void dag_main(const float* __restrict__ hidden, const u32x4* __restrict__ wsB,
              const float* __restrict__ b_init, const float* __restrict__ b_op,
              const float* __restrict__ b_gate, float* __restrict__ out)
{
  __shared__ __align__(16) char smem[2 * BUFB];   // 67584 B (sC overlays)

  const int tid = threadIdx.x;
  const int l   = tid & 63;
  const int w   = tid >> 6;       // wave 0..3 == col-slice
  const int row0 = blockIdx.x * BM;
  const int r   = l & 15;
  const int kg  = l >> 4;

  // A: lane l covers rows row0 + mt*16 + r, k = t*32 + kg*8
  const float* ap0 = hidden + (size_t)(row0 + r) * HID + kg * 8;
  const float* ap1 = ap0 + (size_t)16 * HID;

  // B staging: wave w stages 1-KB chunks [8w, 8w+8); wave 0 also chunk 32
  const u32x4* bsrc = wsB + 512 * w + l;          // + t*NELEM + i*64
  char* wbase = smem + w * 8192 + l * 16;         // + sel*BUFB + i*1024
  // B fragment reads: wave w reads chunks (w*9 + j*3 + pl)
  const char* brd0 = smem + (w * 9 * 64 + l) * 16;

  f32x4 acc[2][3];
  const f32x4 zf = {0.f, 0.f, 0.f, 0.f};
  #pragma unroll
  for (int mt = 0; mt < 2; ++mt)
    #pragma unroll
    for (int j = 0; j < 3; ++j) acc[mt][j] = zf;

  float xs0[8], xs1[8];

#define STAGE(t_, sel_) do {                                       \
    const u32x4* s_ = bsrc + (size_t)NELEM * (t_);                 \
    char* d_ = wbase + (sel_) * BUFB;                              \
    gld_lds16(s_,        d_);                                      \
    gld_lds16(s_ + 64,   d_ + 1024);                               \
    gld_lds16(s_ + 128,  d_ + 2048);                               \
    gld_lds16(s_ + 192,  d_ + 3072);                               \
    gld_lds16(s_ + 256,  d_ + 4096);                               \
    gld_lds16(s_ + 320,  d_ + 5120);                               \
    gld_lds16(s_ + 384,  d_ + 6144);                               \
    gld_lds16(s_ + 448,  d_ + 7168);                               \
    if (w == 0) gld_lds16(s_ + (2048 - 512 * 0), d_ + (32768 - 0));\
  } while (0)
  // note: for w==0, s_+2048 / d_+32768 are relative to wave-0 bases -> chunk 32

  // prologue
  STAGE(0, 0);
  loadA8(ap0, xs0);
  loadA8(ap1, xs1);
  __syncthreads();

  for (int t = 0; t < KSTEPS; ++t) {
    // split current A (registers only)
    Planes PA0 = split8(xs0);
    Planes PA1 = split8(xs1);
    short8 a0p1 = __builtin_bit_cast(short8, PA0.p1);
    short8 a0p2 = __builtin_bit_cast(short8, PA0.p2);
    short8 a0p3 = __builtin_bit_cast(short8, PA0.p3);
    short8 a1p1 = __builtin_bit_cast(short8, PA1.p1);
    short8 a1p2 = __builtin_bit_cast(short8, PA1.p2);
    short8 a1p3 = __builtin_bit_cast(short8, PA1.p3);

    // issue next-tile DMA + A loads (drained at end-of-step barrier)
    if (t + 1 < KSTEPS) {
      STAGE(t + 1, (t + 1) & 1);
      loadA8(ap0 + (t + 1) * 32, xs0);
      loadA8(ap1 + (t + 1) * 32, xs1);
    }

    // MFMA on current buffer
    const char* bb = brd0 + (t & 1) * BUFB;
    #pragma unroll
    for (int j = 0; j < 3; ++j) {
      if (w == 3 && j == 2) continue;        // cols 176..191 don't exist
      short8 b1 = *(const short8*)(bb + (j * 3 + 0) * 1024);
      short8 b2 = *(const short8*)(bb + (j * 3 + 1) * 1024);
      short8 b3 = *(const short8*)(bb + (j * 3 + 2) * 1024);
      {
        f32x4 c = acc[0][j];
        c = mf(a0p1, b1, c); c = mf(a0p1, b2, c); c = mf(a0p2, b1, c);
        c = mf(a0p1, b3, c); c = mf(a0p2, b2, c); c = mf(a0p3, b1, c);
        acc[0][j] = c;
      }
      {
        f32x4 c = acc[1][j];
        c = mf(a1p1, b1, c); c = mf(a1p1, b2, c); c = mf(a1p2, b1, c);
        c = mf(a1p1, b3, c); c = mf(a1p2, b2, c); c = mf(a1p3, b1, c);
        acc[1][j] = c;
      }
    }
    __syncthreads();   // drains DMA + reads; flip buffers
  }
#undef STAGE

  // epilogue: acc -> sC (overlays LDS; safe after final barrier)
  float (*sC)[CPD] = (float(*)[CPD])smem;
  #pragma unroll
  for (int mt = 0; mt < 2; ++mt) {
    #pragma unroll
    for (int j = 0; j < 3; ++j) {
      int col = w * 48 + j * 16 + r;
      if (col < NCOL) {
        int row = mt * 16 + kg * 4;
        sC[row + 0][col] = acc[mt][j][0];
        sC[row + 1][col] = acc[mt][j][1];
        sC[row + 2][col] = acc[mt][j][2];
        sC[row + 3][col] = acc[mt][j][3];
      }
    }
  }
  __syncthreads();

  // per-row sequential DAG: one lane per row
  if (tid < BM) {
    const int rr = tid;
    float Vm[NSLOT], Vs[NSLOT];
    #pragma unroll
    for (int i = 0; i < NSLOT; ++i) {
      float mv = sC[rr][i]      + b_init[i];
      float sv = sC[rr][16 + i] + b_init[16 + i];
      Vm[i] = fabsf(mv);
      Vs[i] = tanhf(sv);
    }
    float G[NSTEP];
    #pragma unroll
    for (int s = 0; s < NSTEP; ++s) {
      float gr = sC[rr][160 + s] + b_gate[s];
      G[s] = 1.0f / (1.0f + expf(-gr));
    }
    #pragma unroll
    for (int s = 0; s < NSTEP; ++s) {
      const float g = G[s];
      float R = 0.f, sp = 1.f;
      #pragma unroll
      for (int i = 0; i < NSLOT; ++i) {
        float Osi = (i < 8 + s) ? (sC[rr][32 + s * 16 + i] + b_op[s * 16 + i]) : 0.f;
        float sgn   = Vs[i] * Vm[i];
        float logm  = logf(fmaxf(Vm[i], 1e-12f));
        float mixed = logm * (1.f - g) + sgn * g;
        R  += Osi * mixed;
        sp *= Vs[i] * (fabsf(Osi) + 1.f);
      }
      float lin_sign = tanhf(R  / 1e-4f);
      float log_sign = tanhf(sp / 1e-4f);
      float vs_new = g * lin_sign + (1.f - g) * log_sign;
      float vm_new = g * fabsf(R) + (1.f - g) * expf(fminf(R, 23.026f));
      Vm[8 + s] = vm_new;
      Vs[8 + s] = vs_new;
    }
    out[row0 + rr] = Vs[NSLOT - 1] * Vm[NSLOT - 1];
  }
}

extern "C" void kernel_launch(void* const* d_in, const int* in_sizes, int n_in,
                              void* d_out, int out_size, void* d_ws, size_t ws_size,
                              hipStream_t stream) {
  (void)in_sizes; (void)n_in; (void)out_size; (void)ws_size;
  const float* hidden = (const float*)d_in[0];
  const float* W_init = (const float*)d_in[1];
  const float* b_init = (const float*)d_in[2];
  const float* W_op   = (const float*)d_in[3];
  const float* b_op   = (const float*)d_in[4];
  const float* W_gate = (const float*)d_in[5];
  const float* b_gate = (const float*)d_in[6];
  float* out = (float*)d_out;
  u32x4* wsB = (u32x4*)d_ws;      // 64 * 2112 * 16 B = 2.06 MiB

  prep_b<<<dim3(704), dim3(64), 0, stream>>>(W_init, W_op, W_gate, wsB);
  dag_main<<<dim3(NROW / BM), dim3(256), 0, stream>>>(hidden, wsB, b_init, b_op,
                                                      b_gate, out);
}